// Round 13
// baseline (225.549 us; speedup 1.0000x reference)
//
#include <hip/hip_runtime.h>
#include <hip/hip_bf16.h>
#include <math.h>

#define N_NODES 100000
#define N_EDGES 1600000
#define IN_SIZE 128
#define FEAT 128      // OUT_SIZE * NUM_HEADS
#define HEADS 8
#define SLOPE 0.01f

#define NSLICE 64
#define SLICE_E (N_EDGES / NSLICE)       // 25000
// count: 8 partitions of 12500 (50KB static LDS hist)
#define NPART_C 8
#define PART_C 12500
// scatter: 4 partitions of 25000 (100KB LDS cursor)
#define NPART_S 4
#define PART_S 25000

#define GBM 128
#define AP 136   // padded LDS row stride in bf16 elements
#define GEMM_BLOCKS ((N_NODES + GBM - 1) / GBM)     // 782

// bf16 helpers
__device__ __forceinline__ unsigned int f32_to_bf16_rne(float f) {
    unsigned int u = __float_as_uint(f);
    return (u + 0x7FFFu + ((u >> 16) & 1u)) >> 16;
}
__device__ __forceinline__ unsigned int pk_bf16(float lo, float hi) {
    __hip_bfloat162 p = __float22bfloat162_rn(make_float2(lo, hi));
    return *(unsigned int*)&p;   // v_cvt_pk_bf16_f32 (RNE), lo in low 16 bits
}
__device__ __forceinline__ float bf16lo_to_f32(unsigned int u) {
    return __uint_as_float(u << 16);
}
__device__ __forceinline__ float bf16hi_to_f32(unsigned int u) {
    return __uint_as_float(u & 0xFFFF0000u);
}

typedef __attribute__((ext_vector_type(8))) short short8v;
typedef __attribute__((ext_vector_type(4))) float f32x4;

// ---------------- MFMA bf16 GEMM + fused el/er -------------------------------
// A (x tile) staged in LDS (34.8KB -> 4 blocks/CU); B (W, 64KB, L2-hot) loaded
// per-ks directly into registers. 4 waves; wave w owns rows [w*32, w*32+32).
__global__ __launch_bounds__(256, 3) void gemm_mfma(
    const float* __restrict__ x, const float* __restrict__ W,
    const float* __restrict__ bias, const float* __restrict__ al,
    const float* __restrict__ ar, unsigned short* __restrict__ Zb,
    float* __restrict__ el, float* __restrict__ er)
{
    __shared__ unsigned short As[GBM][AP];   // x tile bf16 (later reused for Z)
    int tid = threadIdx.x;
    int row0 = blockIdx.x * GBM;

    // stage A: x[row0..+128][0..128) f32 -> bf16  (4096 float4, 16/thread)
#pragma unroll
    for (int i = 0; i < 16; i++) {
        int li = i * 256 + tid;
        int r = li >> 5, c4 = li & 31;
        int grow = row0 + r;
        float4 v = make_float4(0.f, 0.f, 0.f, 0.f);
        if (grow < N_NODES)
            v = *(const float4*)(x + (size_t)grow * IN_SIZE + c4 * 4);
        *(uint2*)&As[r][c4 * 4] = make_uint2(pk_bf16(v.x, v.y), pk_bf16(v.z, v.w));
    }
    __syncthreads();

    int wv = tid >> 6, l = tid & 63;
    int lr = l & 15, lk = l >> 4;

    f32x4 acc[2][8];
#pragma unroll
    for (int mf = 0; mf < 2; mf++)
#pragma unroll
        for (int nf = 0; nf < 8; nf++) acc[mf][nf] = (f32x4){0.f, 0.f, 0.f, 0.f};

#pragma unroll
    for (int ks = 0; ks < 4; ks++) {
        short8v a[2], b[8];
#pragma unroll
        for (int mf = 0; mf < 2; mf++)
            a[mf] = *(const short8v*)&As[wv * 32 + mf * 16 + lr][ks * 32 + lk * 8];
#pragma unroll
        for (int nf = 0; nf < 8; nf++) {
            const float* wp = W + (size_t)(nf * 16 + lr) * IN_SIZE + ks * 32 + lk * 8;
            float4 w0 = *(const float4*)wp;
            float4 w1 = *(const float4*)(wp + 4);
            uint4 qq = make_uint4(pk_bf16(w0.x, w0.y), pk_bf16(w0.z, w0.w),
                                  pk_bf16(w1.x, w1.y), pk_bf16(w1.z, w1.w));
            b[nf] = *(short8v*)&qq;
        }
#pragma unroll
        for (int mf = 0; mf < 2; mf++)
#pragma unroll
            for (int nf = 0; nf < 8; nf++)
                acc[mf][nf] = __builtin_amdgcn_mfma_f32_16x16x32_bf16(
                    a[mf], b[nf], acc[mf][nf], 0, 0, 0);
    }

    // epilogue: bias + bf16, store into As (each wave writes only its own rows)
    float bias_r[8];
#pragma unroll
    for (int nf = 0; nf < 8; nf++) bias_r[nf] = bias[nf * 16 + lr];
#pragma unroll
    for (int mf = 0; mf < 2; mf++)
#pragma unroll
        for (int nf = 0; nf < 8; nf++)
#pragma unroll
            for (int ri = 0; ri < 4; ri++) {
                int r = wv * 32 + mf * 16 + lk * 4 + ri;
                As[r][nf * 16 + lr] =
                    (unsigned short)f32_to_bf16_rne(acc[mf][nf][ri] + bias_r[nf]);
            }
    __syncthreads();

    // coalesced Zb write: 128 rows x 16 uint4
#pragma unroll
    for (int i = 0; i < 8; i++) {
        int li = i * 256 + tid;
        int r = li >> 4, c = li & 15;
        int grow = row0 + r;
        if (grow < N_NODES)
            *(uint4*)(Zb + (size_t)grow * FEAT + c * 8) = *(uint4*)&As[r][c * 8];
    }

    // el/er: 2 threads per row; features f = half*64 + f', head = f'&7
    {
        int r = tid >> 1, half = tid & 1;
        int grow = row0 + r;
        float pl[8], pr[8];
#pragma unroll
        for (int h = 0; h < 8; h++) { pl[h] = 0.f; pr[h] = 0.f; }
        int f0 = half * 64;
        for (int i = 0; i < 32; i++) {
            unsigned int z2 = *(const unsigned int*)&As[r][f0 + i * 2];
            float2 a2 = *(const float2*)(al + f0 + i * 2);
            float2 b2 = *(const float2*)(ar + f0 + i * 2);
            float z0 = bf16lo_to_f32(z2), z1 = bf16hi_to_f32(z2);
            int h0 = (i * 2) & 7;
            pl[h0] += z0 * a2.x;     pr[h0] += z0 * b2.x;
            pl[h0 + 1] += z1 * a2.y; pr[h0 + 1] += z1 * b2.y;
        }
#pragma unroll
        for (int h = 0; h < 8; h++) {
            pl[h] += __shfl_xor(pl[h], 1, 64);
            pr[h] += __shfl_xor(pr[h], 1, 64);
        }
        if (half == 0 && grow < N_NODES) {
            *(float4*)(el + (size_t)grow * HEADS)     = make_float4(pl[0], pl[1], pl[2], pl[3]);
            *(float4*)(el + (size_t)grow * HEADS + 4) = make_float4(pl[4], pl[5], pl[6], pl[7]);
            *(float4*)(er + (size_t)grow * HEADS)     = make_float4(pr[0], pr[1], pr[2], pr[3]);
            *(float4*)(er + (size_t)grow * HEADS + 4) = make_float4(pr[4], pr[5], pr[6], pr[7]);
        }
    }
}

// ---------- CSR build, ZERO global atomics (counting sort) -------------------
__global__ __launch_bounds__(256) void count_kernel(
    const int* __restrict__ row, unsigned char* __restrict__ counts)
{
    __shared__ unsigned int ldsH[PART_C];   // 50 KB
    int tid = threadIdx.x;
    int p = blockIdx.x & (NPART_C - 1);
    int s = blockIdx.x >> 3;
    int lo = p * PART_C;
    for (int i = tid; i < PART_C; i += 256) ldsH[i] = 0;
    __syncthreads();
    int elo = s * SLICE_E;
    for (int e = elo + tid * 4; e < elo + SLICE_E; e += 256 * 4) {
        int4 r4 = *(const int4*)(row + e);
        int r[4] = {r4.x, r4.y, r4.z, r4.w};
#pragma unroll
        for (int i = 0; i < 4; i++) {
            unsigned int d = (unsigned int)(r[i] - lo);
            if (d < PART_C) atomicAdd(&ldsH[d], 1u);
        }
    }
    __syncthreads();
    for (int i = tid; i < PART_C; i += 256)
        counts[(size_t)(lo + i) * NSLICE + s] = (unsigned char)ldsH[i];
}

// ---------------- scans ----------------
__global__ __launch_bounds__(256) void scan1_kernel(
    unsigned char* __restrict__ counts, int* __restrict__ off, int* __restrict__ parts)
{
    __shared__ int tsum[256];
    int t = threadIdx.x;
    int base = blockIdx.x * 1024 + t * 4;
    int v[4];
#pragma unroll
    for (int i = 0; i < 4; i++) {
        int n = base + i;
        int tot = 0;
        if (n < N_NODES) {
            uint4* cp = (uint4*)(counts + (size_t)n * NSLICE);
            unsigned int w[16];
#pragma unroll
            for (int q = 0; q < 4; q++) {
                uint4 qq = cp[q];
                w[q * 4 + 0] = qq.x; w[q * 4 + 1] = qq.y;
                w[q * 4 + 2] = qq.z; w[q * 4 + 3] = qq.w;
            }
            unsigned int run = 0, o[16];
#pragma unroll
            for (int k = 0; k < 16; k++) {
                unsigned int xw = w[k], ow = 0;
#pragma unroll
                for (int bb = 0; bb < 4; bb++) {
                    ow |= (run & 0xffu) << (8 * bb);
                    run += (xw >> (8 * bb)) & 0xffu;
                }
                o[k] = ow;
            }
#pragma unroll
            for (int q = 0; q < 4; q++)
                cp[q] = make_uint4(o[q * 4], o[q * 4 + 1], o[q * 4 + 2], o[q * 4 + 3]);
            tot = (int)run;
        }
        v[i] = tot;
    }
    int ssum = v[0] + v[1] + v[2] + v[3];
    tsum[t] = ssum;
    __syncthreads();
    for (int st = 1; st < 256; st <<= 1) {
        int add = (t >= st) ? tsum[t - st] : 0;
        __syncthreads();
        tsum[t] += add;
        __syncthreads();
    }
    int texcl = tsum[t] - ssum;
    if (t == 255) parts[blockIdx.x] = tsum[255];
    int run = texcl;
#pragma unroll
    for (int i = 0; i < 4; i++) {
        int idx = base + i;
        if (idx < N_NODES) off[idx] = run;
        run += v[i];
    }
}

__global__ __launch_bounds__(128) void scan2_kernel(int* __restrict__ parts, int nparts)
{
    __shared__ int l[128];
    int t = threadIdx.x;
    l[t] = (t < nparts) ? parts[t] : 0;
    __syncthreads();
    for (int st = 1; st < 128; st <<= 1) {
        int add = (t >= st) ? l[t - st] : 0;
        __syncthreads();
        l[t] += add;
        __syncthreads();
    }
    if (t < nparts) parts[t] = (t > 0) ? l[t - 1] : 0;  // exclusive
}

__global__ __launch_bounds__(256) void scan3_kernel(int* __restrict__ off, const int* __restrict__ parts)
{
    int base = blockIdx.x * 1024 + threadIdx.x * 4;
    int p = parts[blockIdx.x];
#pragma unroll
    for (int i = 0; i < 4; i++) {
        int idx = base + i;
        if (idx < N_NODES) off[idx] += p;
    }
    if (blockIdx.x == 0 && threadIdx.x == 0) off[N_NODES] = N_EDGES;
}

// scatter: 4 partitions x 64 slices; LDS cursor (100KB), LDS atomics only
__global__ __launch_bounds__(512) void scatter_kernel(
    const int* __restrict__ row, const int* __restrict__ col,
    const int* __restrict__ off, const unsigned char* __restrict__ counts,
    int* __restrict__ csr)
{
    extern __shared__ int cur[];   // PART_S ints = 100 KB
    int tid = threadIdx.x;
    int p = blockIdx.x & (NPART_S - 1);
    int s = blockIdx.x >> 2;
    int lo = p * PART_S;
    for (int i = tid; i < PART_S; i += 512)
        cur[i] = off[lo + i] + (int)counts[(size_t)(lo + i) * NSLICE + s];
    __syncthreads();
    int elo = s * SLICE_E;
    for (int e = elo + tid * 4; e < elo + SLICE_E; e += 512 * 4) {
        int4 r4 = *(const int4*)(row + e);
        int4 c4 = *(const int4*)(col + e);
        int r[4] = {r4.x, r4.y, r4.z, r4.w};
        int c[4] = {c4.x, c4.y, c4.z, c4.w};
#pragma unroll
        for (int i = 0; i < 4; i++) {
            unsigned int d = (unsigned int)(r[i] - lo);
            if (d < PART_S) {
                int pos = atomicAdd(&cur[d], 1);
                csr[pos] = c[i];
            }
        }
    }
}

// ---------- node kernel: wave-synchronous, 1 wave per node, no LDS -----------
__global__ __launch_bounds__(256) void node_kernel(
    const int* __restrict__ off, const int* __restrict__ csr,
    const unsigned int* __restrict__ ZbU, const float* __restrict__ el,
    const float* __restrict__ er, float* __restrict__ out)
{
    int wv = threadIdx.x >> 6, l = threadIdx.x & 63;
    int n = blockIdx.x * 4 + wv;
    if (n >= N_NODES) return;
    int start = off[n];
    int deg = off[n + 1] - start;
    int l2 = l * 2;
    if (deg == 0) {
        *(float2*)(out + (size_t)n * FEAT + l2) = make_float2(0.f, 0.f);
        return;
    }
    int h = l & 7, jme = l >> 3;
    int h0 = l2 & 7;
    float eln = el[n * HEADS + h];
    float acc0 = 0.f, acc1 = 0.f, sp = 0.f;

    for (int j0 = 0; j0 < deg; j0 += 8) {
        int jn = min(8, deg - j0);
        int jj = l & 7;
        int cidx = (jj < jn) ? (start + j0 + jj) : start;
        int cval = csr[cidx];
        unsigned int zr[8];
#pragma unroll
        for (int j = 0; j < 8; j++) {
            int cj = __shfl(cval, j, 64);
            zr[j] = ZbU[(size_t)cj * 64 + l];
        }
        float ex = 0.f;
        if (jme < jn) {
            int cme = __shfl(cval, jme, 64);
            float a = eln + er[cme * HEADS + h];
            a = (a >= 0.f) ? a : a * SLOPE;
            ex = __expf(a);
            sp += ex;
        }
#pragma unroll
        for (int j = 0; j < 8; j++) {
            float e_lo = __shfl(ex, j * 8 + h0, 64);
            float e_hi = __shfl(ex, j * 8 + h0 + 1, 64);
            acc0 += e_lo * bf16lo_to_f32(zr[j]);
            acc1 += e_hi * bf16hi_to_f32(zr[j]);
        }
    }

    sp += __shfl_xor(sp, 8, 64);
    sp += __shfl_xor(sp, 16, 64);
    sp += __shfl_xor(sp, 32, 64);
    float s_lo = __shfl(sp, h0, 64);
    float s_hi = __shfl(sp, h0 + 1, 64);
    *(float2*)(out + (size_t)n * FEAT + l2) =
        make_float2(acc0 / s_lo, acc1 / s_hi);
}

extern "C" void kernel_launch(void* const* d_in, const int* in_sizes, int n_in,
                              void* d_out, int out_size, void* d_ws, size_t ws_size,
                              hipStream_t stream)
{
    const float* x  = (const float*)d_in[0];
    const float* W  = (const float*)d_in[1];
    const float* b  = (const float*)d_in[2];
    const float* al = (const float*)d_in[3];
    const float* ar = (const float*)d_in[4];
    const int* row  = (const int*)d_in[5];
    const int* col  = (const int*)d_in[6];
    float* out = (float*)d_out;

    unsigned short* Zb = (unsigned short*)d_ws;                    // 25.6 MB
    float* el   = (float*)(Zb + (size_t)N_NODES * FEAT);           // 3.2 MB
    float* er   = el + (size_t)N_NODES * HEADS;                    // 3.2 MB
    unsigned char* counts = (unsigned char*)(er + (size_t)N_NODES * HEADS); // 6.4 MB
    int* off    = (int*)(counts + (size_t)N_NODES * NSLICE);       // 400 KB
    int* csr    = off + (N_NODES + 1);                             // 6.4 MB
    int* parts  = csr + N_EDGES;                                   // small

    gemm_mfma<<<GEMM_BLOCKS, 256, 0, stream>>>(x, W, b, al, ar, Zb, el, er);

    count_kernel<<<NSLICE * NPART_C, 256, 0, stream>>>(row, counts);
    int nparts = (N_NODES + 1023) / 1024;  // 98
    scan1_kernel<<<nparts, 256, 0, stream>>>(counts, off, parts);
    scan2_kernel<<<1, 128, 0, stream>>>(parts, nparts);
    scan3_kernel<<<nparts, 256, 0, stream>>>(off, parts);
    scatter_kernel<<<NSLICE * NPART_S, 512, PART_S * sizeof(int), stream>>>(
        row, col, off, counts, csr);

    node_kernel<<<(N_NODES + 3) / 4, 256, 0, stream>>>(off, csr, (const unsigned int*)Zb, el, er, out);
}

// Round 14
// 212.144 us; speedup vs baseline: 1.0632x; 1.0632x over previous
//
#include <hip/hip_runtime.h>
#include <hip/hip_bf16.h>
#include <math.h>

#define N_NODES 100000
#define N_EDGES 1600000
#define IN_SIZE 128
#define FEAT 128      // OUT_SIZE * NUM_HEADS
#define HEADS 8
#define SLOPE 0.01f

#define NSLICE 64
#define SLICE_E (N_EDGES / NSLICE)       // 25000
// count: 8 partitions of 12500 (50KB static LDS hist)
#define NPART_C 8
#define PART_C 12500
// scatter: 4 partitions of 25000 (100KB LDS cursor)
#define NPART_S 4
#define PART_S 25000

#define GBM 128
#define KB 64        // K-half width
#define APA 72       // padded LDS row stride in shorts (144B: 16B-aligned, bank-friendly)
#define GEMM_BLOCKS ((N_NODES + GBM - 1) / GBM)     // 782

// bf16 helpers
__device__ __forceinline__ unsigned int f32_to_bf16_rne(float f) {
    unsigned int u = __float_as_uint(f);
    return (u + 0x7FFFu + ((u >> 16) & 1u)) >> 16;
}
__device__ __forceinline__ unsigned int pk_bf16(float lo, float hi) {
    __hip_bfloat162 p = __float22bfloat162_rn(make_float2(lo, hi));
    return *(unsigned int*)&p;   // v_cvt_pk_bf16_f32 (RNE), lo in low 16 bits
}
__device__ __forceinline__ float bf16lo_to_f32(unsigned int u) {
    return __uint_as_float(u << 16);
}
__device__ __forceinline__ float bf16hi_to_f32(unsigned int u) {
    return __uint_as_float(u & 0xFFFF0000u);
}

typedef __attribute__((ext_vector_type(8))) short short8v;
typedef __attribute__((ext_vector_type(4))) float f32x4;

// ---------------- MFMA bf16 GEMM + fused el/er -------------------------------
// K split into 2 halves of 64: LDS = 2 x [128][72] bf16 = 36.9KB -> 4 blocks/CU.
// 4 waves; wave w owns rows [w*32, w*32+32). Z reuses A/B LDS for the epilogue.
__global__ __launch_bounds__(256) void gemm_mfma(
    const float* __restrict__ x, const float* __restrict__ W,
    const float* __restrict__ bias, const float* __restrict__ al,
    const float* __restrict__ ar, unsigned short* __restrict__ Zb,
    float* __restrict__ el, float* __restrict__ er)
{
    __shared__ unsigned short As[GBM][APA];
    __shared__ unsigned short Bs[FEAT][APA];
    int tid = threadIdx.x;
    int row0 = blockIdx.x * GBM;
    int wv = tid >> 6, l = tid & 63;
    int lr = l & 15, lk = l >> 4;

    f32x4 acc[2][8];
#pragma unroll
    for (int mf = 0; mf < 2; mf++)
#pragma unroll
        for (int nf = 0; nf < 8; nf++) acc[mf][nf] = (f32x4){0.f, 0.f, 0.f, 0.f};

#pragma unroll
    for (int kh = 0; kh < 2; kh++) {
        if (kh) __syncthreads();   // previous half fully consumed
        // stage A half: 128 rows x 64 k (2048 float4, 8/thread)
#pragma unroll
        for (int i = 0; i < 8; i++) {
            int li = i * 256 + tid;
            int r = li >> 4, c4 = li & 15;
            int grow = row0 + r;
            float4 v = make_float4(0.f, 0.f, 0.f, 0.f);
            if (grow < N_NODES)
                v = *(const float4*)(x + (size_t)grow * IN_SIZE + kh * KB + c4 * 4);
            *(uint2*)&As[r][c4 * 4] = make_uint2(pk_bf16(v.x, v.y), pk_bf16(v.z, v.w));
        }
        // stage B half: 128 f x 64 k
#pragma unroll
        for (int i = 0; i < 8; i++) {
            int li = i * 256 + tid;
            int f = li >> 4, c4 = li & 15;
            float4 v = *(const float4*)(W + (size_t)f * IN_SIZE + kh * KB + c4 * 4);
            *(uint2*)&Bs[f][c4 * 4] = make_uint2(pk_bf16(v.x, v.y), pk_bf16(v.z, v.w));
        }
        __syncthreads();
#pragma unroll
        for (int ks = 0; ks < 2; ks++) {
            short8v a[2], b[8];
#pragma unroll
            for (int mf = 0; mf < 2; mf++)
                a[mf] = *(const short8v*)&As[wv * 32 + mf * 16 + lr][ks * 32 + lk * 8];
#pragma unroll
            for (int nf = 0; nf < 8; nf++)
                b[nf] = *(const short8v*)&Bs[nf * 16 + lr][ks * 32 + lk * 8];
#pragma unroll
            for (int mf = 0; mf < 2; mf++)
#pragma unroll
                for (int nf = 0; nf < 8; nf++)
                    acc[mf][nf] = __builtin_amdgcn_mfma_f32_16x16x32_bf16(
                        a[mf], b[nf], acc[mf][nf], 0, 0, 0);
        }
    }
    __syncthreads();

    // epilogue: bias + bf16 -> Z into LDS (cols 0..63 in As, 64..127 in Bs)
    float bias_r[8];
#pragma unroll
    for (int nf = 0; nf < 8; nf++) bias_r[nf] = bias[nf * 16 + lr];
#pragma unroll
    for (int mf = 0; mf < 2; mf++)
#pragma unroll
        for (int nf = 0; nf < 8; nf++)
#pragma unroll
            for (int ri = 0; ri < 4; ri++) {
                int r = wv * 32 + mf * 16 + lk * 4 + ri;
                unsigned short zb =
                    (unsigned short)f32_to_bf16_rne(acc[mf][nf][ri] + bias_r[nf]);
                if (nf < 4) As[r][nf * 16 + lr] = zb;
                else        Bs[r][nf * 16 + lr - 64] = zb;
            }
    __syncthreads();

    // coalesced Zb write: 128 rows x 16 uint4 (c<8 from As, else Bs)
#pragma unroll
    for (int i = 0; i < 8; i++) {
        int li = i * 256 + tid;
        int r = li >> 4, c = li & 15;
        int grow = row0 + r;
        if (grow < N_NODES) {
            uint4 v = (c < 8) ? *(uint4*)&As[r][c * 8]
                              : *(uint4*)&Bs[r][(c - 8) * 8];
            *(uint4*)(Zb + (size_t)grow * FEAT + c * 8) = v;
        }
    }

    // el/er: 2 threads per row; half 0 reads As (f 0..63), half 1 reads Bs
    {
        int r = tid >> 1, half = tid & 1;
        int grow = row0 + r;
        float pl[8], pr[8];
#pragma unroll
        for (int h = 0; h < 8; h++) { pl[h] = 0.f; pr[h] = 0.f; }
        int f0 = half * 64;
        const unsigned short* zrow = half ? &Bs[r][0] : &As[r][0];
        for (int i = 0; i < 32; i++) {
            unsigned int z2 = *(const unsigned int*)(zrow + i * 2);
            float2 a2 = *(const float2*)(al + f0 + i * 2);
            float2 b2 = *(const float2*)(ar + f0 + i * 2);
            float z0 = bf16lo_to_f32(z2), z1 = bf16hi_to_f32(z2);
            int h0 = (i * 2) & 7;
            pl[h0] += z0 * a2.x;     pr[h0] += z0 * b2.x;
            pl[h0 + 1] += z1 * a2.y; pr[h0 + 1] += z1 * b2.y;
        }
#pragma unroll
        for (int h = 0; h < 8; h++) {
            pl[h] += __shfl_xor(pl[h], 1, 64);
            pr[h] += __shfl_xor(pr[h], 1, 64);
        }
        if (half == 0 && grow < N_NODES) {
            *(float4*)(el + (size_t)grow * HEADS)     = make_float4(pl[0], pl[1], pl[2], pl[3]);
            *(float4*)(el + (size_t)grow * HEADS + 4) = make_float4(pl[4], pl[5], pl[6], pl[7]);
            *(float4*)(er + (size_t)grow * HEADS)     = make_float4(pr[0], pr[1], pr[2], pr[3]);
            *(float4*)(er + (size_t)grow * HEADS + 4) = make_float4(pr[4], pr[5], pr[6], pr[7]);
        }
    }
}

// ---------- CSR build, ZERO global atomics (counting sort) -------------------
__global__ __launch_bounds__(256) void count_kernel(
    const int* __restrict__ row, unsigned char* __restrict__ counts)
{
    __shared__ unsigned int ldsH[PART_C];   // 50 KB
    int tid = threadIdx.x;
    int p = blockIdx.x & (NPART_C - 1);
    int s = blockIdx.x >> 3;
    int lo = p * PART_C;
    for (int i = tid; i < PART_C; i += 256) ldsH[i] = 0;
    __syncthreads();
    int elo = s * SLICE_E;
    for (int e = elo + tid * 4; e < elo + SLICE_E; e += 256 * 4) {
        int4 r4 = *(const int4*)(row + e);
        int r[4] = {r4.x, r4.y, r4.z, r4.w};
#pragma unroll
        for (int i = 0; i < 4; i++) {
            unsigned int d = (unsigned int)(r[i] - lo);
            if (d < PART_C) atomicAdd(&ldsH[d], 1u);
        }
    }
    __syncthreads();
    for (int i = tid; i < PART_C; i += 256)
        counts[(size_t)(lo + i) * NSLICE + s] = (unsigned char)ldsH[i];
}

// ---------------- scans ----------------
__global__ __launch_bounds__(256) void scan1_kernel(
    unsigned char* __restrict__ counts, int* __restrict__ off, int* __restrict__ parts)
{
    __shared__ int tsum[256];
    int t = threadIdx.x;
    int base = blockIdx.x * 1024 + t * 4;
    int v[4];
#pragma unroll
    for (int i = 0; i < 4; i++) {
        int n = base + i;
        int tot = 0;
        if (n < N_NODES) {
            uint4* cp = (uint4*)(counts + (size_t)n * NSLICE);
            unsigned int w[16];
#pragma unroll
            for (int q = 0; q < 4; q++) {
                uint4 qq = cp[q];
                w[q * 4 + 0] = qq.x; w[q * 4 + 1] = qq.y;
                w[q * 4 + 2] = qq.z; w[q * 4 + 3] = qq.w;
            }
            unsigned int run = 0, o[16];
#pragma unroll
            for (int k = 0; k < 16; k++) {
                unsigned int xw = w[k], ow = 0;
#pragma unroll
                for (int bb = 0; bb < 4; bb++) {
                    ow |= (run & 0xffu) << (8 * bb);
                    run += (xw >> (8 * bb)) & 0xffu;
                }
                o[k] = ow;
            }
#pragma unroll
            for (int q = 0; q < 4; q++)
                cp[q] = make_uint4(o[q * 4], o[q * 4 + 1], o[q * 4 + 2], o[q * 4 + 3]);
            tot = (int)run;
        }
        v[i] = tot;
    }
    int ssum = v[0] + v[1] + v[2] + v[3];
    tsum[t] = ssum;
    __syncthreads();
    for (int st = 1; st < 256; st <<= 1) {
        int add = (t >= st) ? tsum[t - st] : 0;
        __syncthreads();
        tsum[t] += add;
        __syncthreads();
    }
    int texcl = tsum[t] - ssum;
    if (t == 255) parts[blockIdx.x] = tsum[255];
    int run = texcl;
#pragma unroll
    for (int i = 0; i < 4; i++) {
        int idx = base + i;
        if (idx < N_NODES) off[idx] = run;
        run += v[i];
    }
}

__global__ __launch_bounds__(128) void scan2_kernel(int* __restrict__ parts, int nparts)
{
    __shared__ int l[128];
    int t = threadIdx.x;
    l[t] = (t < nparts) ? parts[t] : 0;
    __syncthreads();
    for (int st = 1; st < 128; st <<= 1) {
        int add = (t >= st) ? l[t - st] : 0;
        __syncthreads();
        l[t] += add;
        __syncthreads();
    }
    if (t < nparts) parts[t] = (t > 0) ? l[t - 1] : 0;  // exclusive
}

__global__ __launch_bounds__(256) void scan3_kernel(int* __restrict__ off, const int* __restrict__ parts)
{
    int base = blockIdx.x * 1024 + threadIdx.x * 4;
    int p = parts[blockIdx.x];
#pragma unroll
    for (int i = 0; i < 4; i++) {
        int idx = base + i;
        if (idx < N_NODES) off[idx] += p;
    }
    if (blockIdx.x == 0 && threadIdx.x == 0) off[N_NODES] = N_EDGES;
}

// scatter: 4 partitions x 64 slices; LDS cursor (100KB), LDS atomics only
__global__ __launch_bounds__(512) void scatter_kernel(
    const int* __restrict__ row, const int* __restrict__ col,
    const int* __restrict__ off, const unsigned char* __restrict__ counts,
    int* __restrict__ csr)
{
    extern __shared__ int cur[];   // PART_S ints = 100 KB
    int tid = threadIdx.x;
    int p = blockIdx.x & (NPART_S - 1);
    int s = blockIdx.x >> 2;
    int lo = p * PART_S;
    for (int i = tid; i < PART_S; i += 512)
        cur[i] = off[lo + i] + (int)counts[(size_t)(lo + i) * NSLICE + s];
    __syncthreads();
    int elo = s * SLICE_E;
    for (int e = elo + tid * 4; e < elo + SLICE_E; e += 512 * 4) {
        int4 r4 = *(const int4*)(row + e);
        int4 c4 = *(const int4*)(col + e);
        int r[4] = {r4.x, r4.y, r4.z, r4.w};
        int c[4] = {c4.x, c4.y, c4.z, c4.w};
#pragma unroll
        for (int i = 0; i < 4; i++) {
            unsigned int d = (unsigned int)(r[i] - lo);
            if (d < PART_S) {
                int pos = atomicAdd(&cur[d], 1);
                csr[pos] = c[i];
            }
        }
    }
}

// ---------- node kernel: wave-synchronous, 1 wave per node, no LDS -----------
__global__ __launch_bounds__(256) void node_kernel(
    const int* __restrict__ off, const int* __restrict__ csr,
    const unsigned int* __restrict__ ZbU, const float* __restrict__ el,
    const float* __restrict__ er, float* __restrict__ out)
{
    int wv = threadIdx.x >> 6, l = threadIdx.x & 63;
    int n = blockIdx.x * 4 + wv;
    if (n >= N_NODES) return;
    int start = off[n];
    int deg = off[n + 1] - start;
    int l2 = l * 2;
    if (deg == 0) {
        *(float2*)(out + (size_t)n * FEAT + l2) = make_float2(0.f, 0.f);
        return;
    }
    int h = l & 7, jme = l >> 3;
    int h0 = l2 & 7;
    float eln = el[n * HEADS + h];
    float acc0 = 0.f, acc1 = 0.f, sp = 0.f;

    for (int j0 = 0; j0 < deg; j0 += 8) {
        int jn = min(8, deg - j0);
        int jj = l & 7;
        int cidx = (jj < jn) ? (start + j0 + jj) : start;
        int cval = csr[cidx];
        unsigned int zr[8];
#pragma unroll
        for (int j = 0; j < 8; j++) {
            int cj = __shfl(cval, j, 64);
            zr[j] = ZbU[(size_t)cj * 64 + l];
        }
        float ex = 0.f;
        if (jme < jn) {
            int cme = __shfl(cval, jme, 64);
            float a = eln + er[cme * HEADS + h];
            a = (a >= 0.f) ? a : a * SLOPE;
            ex = __expf(a);
            sp += ex;
        }
#pragma unroll
        for (int j = 0; j < 8; j++) {
            float e_lo = __shfl(ex, j * 8 + h0, 64);
            float e_hi = __shfl(ex, j * 8 + h0 + 1, 64);
            acc0 += e_lo * bf16lo_to_f32(zr[j]);
            acc1 += e_hi * bf16hi_to_f32(zr[j]);
        }
    }

    sp += __shfl_xor(sp, 8, 64);
    sp += __shfl_xor(sp, 16, 64);
    sp += __shfl_xor(sp, 32, 64);
    float s_lo = __shfl(sp, h0, 64);
    float s_hi = __shfl(sp, h0 + 1, 64);
    *(float2*)(out + (size_t)n * FEAT + l2) =
        make_float2(acc0 / s_lo, acc1 / s_hi);
}

extern "C" void kernel_launch(void* const* d_in, const int* in_sizes, int n_in,
                              void* d_out, int out_size, void* d_ws, size_t ws_size,
                              hipStream_t stream)
{
    const float* x  = (const float*)d_in[0];
    const float* W  = (const float*)d_in[1];
    const float* b  = (const float*)d_in[2];
    const float* al = (const float*)d_in[3];
    const float* ar = (const float*)d_in[4];
    const int* row  = (const int*)d_in[5];
    const int* col  = (const int*)d_in[6];
    float* out = (float*)d_out;

    unsigned short* Zb = (unsigned short*)d_ws;                    // 25.6 MB
    float* el   = (float*)(Zb + (size_t)N_NODES * FEAT);           // 3.2 MB
    float* er   = el + (size_t)N_NODES * HEADS;                    // 3.2 MB
    unsigned char* counts = (unsigned char*)(er + (size_t)N_NODES * HEADS); // 6.4 MB
    int* off    = (int*)(counts + (size_t)N_NODES * NSLICE);       // 400 KB
    int* csr    = off + (N_NODES + 1);                             // 6.4 MB
    int* parts  = csr + N_EDGES;                                   // small

    gemm_mfma<<<GEMM_BLOCKS, 256, 0, stream>>>(x, W, b, al, ar, Zb, el, er);

    count_kernel<<<NSLICE * NPART_C, 256, 0, stream>>>(row, counts);
    int nparts = (N_NODES + 1023) / 1024;  // 98
    scan1_kernel<<<nparts, 256, 0, stream>>>(counts, off, parts);
    scan2_kernel<<<1, 128, 0, stream>>>(parts, nparts);
    scan3_kernel<<<nparts, 256, 0, stream>>>(off, parts);
    scatter_kernel<<<NSLICE * NPART_S, 512, PART_S * sizeof(int), stream>>>(
        row, col, off, counts, csr);

    node_kernel<<<(N_NODES + 3) / 4, 256, 0, stream>>>(off, csr, (const unsigned int*)Zb, el, er, out);
}

// Round 15
// 169.904 us; speedup vs baseline: 1.3275x; 1.2486x over previous
//
#include <hip/hip_runtime.h>
#include <hip/hip_bf16.h>
#include <math.h>

#define N_NODES 100000
#define N_EDGES 1600000
#define IN_SIZE 128
#define FEAT 128      // OUT_SIZE * NUM_HEADS
#define HEADS 8
#define SLOPE 0.01f

#define NSLICE 64
#define SLICE_E (N_EDGES / NSLICE)       // 25000
// count: 8 partitions of 12500 (50KB static LDS hist)
#define NPART_C 8
#define PART_C 12500
// scatter: 4 partitions of 25000 (100KB LDS cursor)
#define NPART_S 4
#define PART_S 25000
#define NPARTS_SCAN ((N_NODES + 1023) / 1024)       // 98

#define GBM 128
#define KB 64        // K-half width
#define APA 72       // padded LDS row stride in shorts
#define GEMM_BLOCKS ((N_NODES + GBM - 1) / GBM)     // 782

// bf16 helpers
__device__ __forceinline__ unsigned int f32_to_bf16_rne(float f) {
    unsigned int u = __float_as_uint(f);
    return (u + 0x7FFFu + ((u >> 16) & 1u)) >> 16;
}
__device__ __forceinline__ unsigned int pk_bf16(float lo, float hi) {
    __hip_bfloat162 p = __float22bfloat162_rn(make_float2(lo, hi));
    return *(unsigned int*)&p;
}
__device__ __forceinline__ float bf16lo_to_f32(unsigned int u) {
    return __uint_as_float(u << 16);
}
__device__ __forceinline__ float bf16hi_to_f32(unsigned int u) {
    return __uint_as_float(u & 0xFFFF0000u);
}

typedef __attribute__((ext_vector_type(8))) short short8v;
typedef __attribute__((ext_vector_type(4))) float f32x4;

// ---------------- MFMA bf16 GEMM + register el/er epilogue -------------------
__global__ __launch_bounds__(256) void gemm_mfma(
    const float* __restrict__ x, const float* __restrict__ W,
    const float* __restrict__ bias, const float* __restrict__ al,
    const float* __restrict__ ar, unsigned short* __restrict__ Zb,
    float* __restrict__ el, float* __restrict__ er)
{
    __shared__ unsigned short As[GBM][APA];
    __shared__ unsigned short Bs[FEAT][APA];
    int tid = threadIdx.x;
    int row0 = blockIdx.x * GBM;
    int wv = tid >> 6, l = tid & 63;
    int lr = l & 15, lk = l >> 4;

    f32x4 acc[2][8];
#pragma unroll
    for (int mf = 0; mf < 2; mf++)
#pragma unroll
        for (int nf = 0; nf < 8; nf++) acc[mf][nf] = (f32x4){0.f, 0.f, 0.f, 0.f};

#pragma unroll
    for (int kh = 0; kh < 2; kh++) {
        if (kh) __syncthreads();
#pragma unroll
        for (int i = 0; i < 8; i++) {
            int li = i * 256 + tid;
            int r = li >> 4, c4 = li & 15;
            int grow = row0 + r;
            float4 v = make_float4(0.f, 0.f, 0.f, 0.f);
            if (grow < N_NODES)
                v = *(const float4*)(x + (size_t)grow * IN_SIZE + kh * KB + c4 * 4);
            *(uint2*)&As[r][c4 * 4] = make_uint2(pk_bf16(v.x, v.y), pk_bf16(v.z, v.w));
        }
#pragma unroll
        for (int i = 0; i < 8; i++) {
            int li = i * 256 + tid;
            int f = li >> 4, c4 = li & 15;
            float4 v = *(const float4*)(W + (size_t)f * IN_SIZE + kh * KB + c4 * 4);
            *(uint2*)&Bs[f][c4 * 4] = make_uint2(pk_bf16(v.x, v.y), pk_bf16(v.z, v.w));
        }
        __syncthreads();
#pragma unroll
        for (int ks = 0; ks < 2; ks++) {
            short8v a[2], b[8];
#pragma unroll
            for (int mf = 0; mf < 2; mf++)
                a[mf] = *(const short8v*)&As[wv * 32 + mf * 16 + lr][ks * 32 + lk * 8];
#pragma unroll
            for (int nf = 0; nf < 8; nf++)
                b[nf] = *(const short8v*)&Bs[nf * 16 + lr][ks * 32 + lk * 8];
#pragma unroll
            for (int mf = 0; mf < 2; mf++)
#pragma unroll
                for (int nf = 0; nf < 8; nf++)
                    acc[mf][nf] = __builtin_amdgcn_mfma_f32_16x16x32_bf16(
                        a[mf], b[nf], acc[mf][nf], 0, 0, 0);
        }
    }
    __syncthreads();

    // bias into acc; el/er straight from registers (head = lr&7)
    float bias_r[8], al_r[8], ar_r[8];
#pragma unroll
    for (int nf = 0; nf < 8; nf++) {
        bias_r[nf] = bias[nf * 16 + lr];
        al_r[nf]   = al[nf * 16 + lr];
        ar_r[nf]   = ar[nf * 16 + lr];
    }
#pragma unroll
    for (int mf = 0; mf < 2; mf++)
#pragma unroll
        for (int nf = 0; nf < 8; nf++)
#pragma unroll
            for (int ri = 0; ri < 4; ri++) acc[mf][nf][ri] += bias_r[nf];

#pragma unroll
    for (int mf = 0; mf < 2; mf++)
#pragma unroll
        for (int ri = 0; ri < 4; ri++) {
            float pl = 0.f, pr = 0.f;
#pragma unroll
            for (int nf = 0; nf < 8; nf++) {
                float z = acc[mf][nf][ri];
                pl += z * al_r[nf];
                pr += z * ar_r[nf];
            }
            pl += __shfl_xor(pl, 8, 64);
            pr += __shfl_xor(pr, 8, 64);
            int r = wv * 32 + mf * 16 + lk * 4 + ri;
            int grow = row0 + r;
            if (lr < 8 && grow < N_NODES) {
                el[(size_t)grow * HEADS + lr] = pl;
                er[(size_t)grow * HEADS + lr] = pr;
            }
        }

    // Z (bf16, biased) -> LDS, then coalesced Zb write
#pragma unroll
    for (int mf = 0; mf < 2; mf++)
#pragma unroll
        for (int nf = 0; nf < 8; nf++)
#pragma unroll
            for (int ri = 0; ri < 4; ri++) {
                int r = wv * 32 + mf * 16 + lk * 4 + ri;
                unsigned short zb = (unsigned short)f32_to_bf16_rne(acc[mf][nf][ri]);
                if (nf < 4) As[r][nf * 16 + lr] = zb;
                else        Bs[r][nf * 16 + lr - 64] = zb;
            }
    __syncthreads();
#pragma unroll
    for (int i = 0; i < 8; i++) {
        int li = i * 256 + tid;
        int r = li >> 4, c = li & 15;
        int grow = row0 + r;
        if (grow < N_NODES) {
            uint4 v = (c < 8) ? *(uint4*)&As[r][c * 8]
                              : *(uint4*)&Bs[r][(c - 8) * 8];
            *(uint4*)(Zb + (size_t)grow * FEAT + c * 8) = v;
        }
    }
}

// ---------- CSR build (counting sort, transposed counts) ---------------------
// countsT[s*N + n]: count block (p,s) writes its own contiguous 12.5KB region
// (no cross-block line sharing -> no write amplification).
__global__ __launch_bounds__(256) void count_kernel(
    const int* __restrict__ row, unsigned char* __restrict__ countsT)
{
    __shared__ unsigned int ldsH[PART_C];   // 50 KB
    int tid = threadIdx.x;
    int p = blockIdx.x & (NPART_C - 1);
    int s = blockIdx.x >> 3;
    int lo = p * PART_C;
    for (int i = tid; i < PART_C; i += 256) ldsH[i] = 0;
    __syncthreads();
    int elo = s * SLICE_E;
    for (int e = elo + tid * 4; e < elo + SLICE_E; e += 256 * 4) {
        int4 r4 = *(const int4*)(row + e);
        int r[4] = {r4.x, r4.y, r4.z, r4.w};
#pragma unroll
        for (int i = 0; i < 4; i++) {
            unsigned int d = (unsigned int)(r[i] - lo);
            if (d < PART_C) atomicAdd(&ldsH[d], 1u);
        }
    }
    __syncthreads();
    for (int i = tid; i < PART_C; i += 256)
        countsT[(size_t)s * N_NODES + lo + i] = (unsigned char)ldsH[i];
}

// ---------------- single scan kernel (scan2 merged via last-block-done) ------
// Converts countsT to per-node exclusive slice-prefix (in place, uchar),
// writes per-chunk-partial off[], chunk totals to parts[], and the LAST block
// computes the exclusive chunk-prefix parts2[]. Consumers add parts2[n>>10].
__global__ __launch_bounds__(256) void scan_kernel(
    unsigned char* __restrict__ countsT, int* __restrict__ off,
    int* __restrict__ parts, int* __restrict__ parts2, int* __restrict__ ctr)
{
    __shared__ int tsum[256];
    __shared__ int amLast;
    int t = threadIdx.x;
    if (t == 0) amLast = 0;
    int base = blockIdx.x * 1024 + t * 4;     // N_NODES % 4 == 0: all-or-none valid
    bool valid = base < N_NODES;
    int run0 = 0, run1 = 0, run2 = 0, run3 = 0;
#pragma unroll 4
    for (int s = 0; s < NSLICE; s++) {
        unsigned char* cp = countsT + (size_t)s * N_NODES + base;
        unsigned int w = valid ? *(const unsigned int*)cp : 0u;
        unsigned int ow = (unsigned int)(run0 & 0xff) | ((unsigned int)(run1 & 0xff) << 8) |
                          ((unsigned int)(run2 & 0xff) << 16) | ((unsigned int)(run3 & 0xff) << 24);
        if (valid) *(unsigned int*)cp = ow;
        run0 += w & 0xffu; run1 += (w >> 8) & 0xffu;
        run2 += (w >> 16) & 0xffu; run3 += (w >> 24) & 0xffu;
    }
    int ssum = run0 + run1 + run2 + run3;
    tsum[t] = ssum;
    __syncthreads();
    for (int st = 1; st < 256; st <<= 1) {
        int add = (t >= st) ? tsum[t - st] : 0;
        __syncthreads();
        tsum[t] += add;
        __syncthreads();
    }
    int texcl = tsum[t] - ssum;
    if (valid) {
        off[base + 0] = texcl;
        off[base + 1] = texcl + run0;
        off[base + 2] = texcl + run0 + run1;
        off[base + 3] = texcl + run0 + run1 + run2;
        if (base + 4 == N_NODES) off[N_NODES] = texcl + ssum;  // end sentinel
    }
    if (t == 255) {
        parts[blockIdx.x] = tsum[255];
        __threadfence();
        if (atomicAdd(ctr, 1) == NPARTS_SCAN - 1) amLast = 1;
    }
    __syncthreads();
    if (amLast) {
        __threadfence();
        int v = (t < NPARTS_SCAN) ? parts[t] : 0;
        tsum[t] = v;
        __syncthreads();
        for (int st = 1; st < 128; st <<= 1) {
            int add = (t >= st) ? tsum[t - st] : 0;
            __syncthreads();
            tsum[t] += add;
            __syncthreads();
        }
        if (t < NPARTS_SCAN) parts2[t] = (t > 0) ? tsum[t - 1] : 0;
    }
}

// scatter: 4 partitions x 64 slices; LDS cursor (100KB), LDS atomics only
__global__ __launch_bounds__(1024) void scatter_kernel(
    const int* __restrict__ row, const int* __restrict__ col,
    const int* __restrict__ off, const unsigned char* __restrict__ countsT,
    const int* __restrict__ parts2, int* __restrict__ csr)
{
    extern __shared__ int cur[];   // PART_S ints = 100 KB
    int tid = threadIdx.x;
    int p = blockIdx.x & (NPART_S - 1);
    int s = blockIdx.x >> 2;
    int lo = p * PART_S;
    for (int i = tid; i < PART_S; i += 1024) {
        int n = lo + i;
        cur[i] = off[n] + parts2[n >> 10] + (int)countsT[(size_t)s * N_NODES + n];
    }
    __syncthreads();
    int elo = s * SLICE_E;
    for (int e = elo + tid * 4; e < elo + SLICE_E; e += 1024 * 4) {
        int4 r4 = *(const int4*)(row + e);
        int4 c4 = *(const int4*)(col + e);
        int r[4] = {r4.x, r4.y, r4.z, r4.w};
        int c[4] = {c4.x, c4.y, c4.z, c4.w};
#pragma unroll
        for (int i = 0; i < 4; i++) {
            unsigned int d = (unsigned int)(r[i] - lo);
            if (d < PART_S) {
                int pos = atomicAdd(&cur[d], 1);
                csr[pos] = c[i];
            }
        }
    }
}

// ---------- node kernel: wave-synchronous, 1 wave per node, no LDS -----------
__global__ __launch_bounds__(256) void node_kernel(
    const int* __restrict__ off, const int* __restrict__ parts2,
    const int* __restrict__ csr, const unsigned int* __restrict__ ZbU,
    const float* __restrict__ el, const float* __restrict__ er,
    float* __restrict__ out)
{
    int wv = threadIdx.x >> 6, l = threadIdx.x & 63;
    int n = blockIdx.x * 4 + wv;
    if (n >= N_NODES) return;
    int start = off[n] + parts2[n >> 10];
    int endp  = off[n + 1] + parts2[(n + 1) >> 10];
    int deg = endp - start;
    int l2 = l * 2;
    if (deg == 0) {
        *(float2*)(out + (size_t)n * FEAT + l2) = make_float2(0.f, 0.f);
        return;
    }
    int h = l & 7, jme = l >> 3;
    int h0 = l2 & 7;
    float eln = el[n * HEADS + h];
    float acc0 = 0.f, acc1 = 0.f, sp = 0.f;

    for (int j0 = 0; j0 < deg; j0 += 8) {
        int jn = min(8, deg - j0);
        int jj = l & 7;
        int cidx = (jj < jn) ? (start + j0 + jj) : start;
        int cval = csr[cidx];
        unsigned int zr[8];
#pragma unroll
        for (int j = 0; j < 8; j++) {
            int cj = __shfl(cval, j, 64);
            zr[j] = ZbU[(size_t)cj * 64 + l];
        }
        float ex = 0.f;
        if (jme < jn) {
            int cme = __shfl(cval, jme, 64);
            float a = eln + er[cme * HEADS + h];
            a = (a >= 0.f) ? a : a * SLOPE;
            ex = __expf(a);
            sp += ex;
        }
#pragma unroll
        for (int j = 0; j < 8; j++) {
            float e_lo = __shfl(ex, j * 8 + h0, 64);
            float e_hi = __shfl(ex, j * 8 + h0 + 1, 64);
            acc0 += e_lo * bf16lo_to_f32(zr[j]);
            acc1 += e_hi * bf16hi_to_f32(zr[j]);
        }
    }

    sp += __shfl_xor(sp, 8, 64);
    sp += __shfl_xor(sp, 16, 64);
    sp += __shfl_xor(sp, 32, 64);
    float s_lo = __shfl(sp, h0, 64);
    float s_hi = __shfl(sp, h0 + 1, 64);
    *(float2*)(out + (size_t)n * FEAT + l2) =
        make_float2(acc0 / s_lo, acc1 / s_hi);
}

extern "C" void kernel_launch(void* const* d_in, const int* in_sizes, int n_in,
                              void* d_out, int out_size, void* d_ws, size_t ws_size,
                              hipStream_t stream)
{
    const float* x  = (const float*)d_in[0];
    const float* W  = (const float*)d_in[1];
    const float* b  = (const float*)d_in[2];
    const float* al = (const float*)d_in[3];
    const float* ar = (const float*)d_in[4];
    const int* row  = (const int*)d_in[5];
    const int* col  = (const int*)d_in[6];
    float* out = (float*)d_out;

    unsigned short* Zb = (unsigned short*)d_ws;                    // 25.6 MB
    float* el   = (float*)(Zb + (size_t)N_NODES * FEAT);           // 3.2 MB
    float* er   = el + (size_t)N_NODES * HEADS;                    // 3.2 MB
    unsigned char* countsT = (unsigned char*)(er + (size_t)N_NODES * HEADS); // 6.4 MB
    int* off    = (int*)(countsT + (size_t)NSLICE * N_NODES);      // 400 KB
    int* csr    = off + (N_NODES + 1);                             // 6.4 MB
    int* parts  = csr + N_EDGES;                                   // 128
    int* parts2 = parts + 128;                                     // 128
    int* ctr    = parts2 + 128;                                    // 1

    hipMemsetAsync(ctr, 0, sizeof(int), stream);

    gemm_mfma<<<GEMM_BLOCKS, 256, 0, stream>>>(x, W, b, al, ar, Zb, el, er);
    count_kernel<<<NSLICE * NPART_C, 256, 0, stream>>>(row, countsT);
    scan_kernel<<<NPARTS_SCAN, 256, 0, stream>>>(countsT, off, parts, parts2, ctr);
    scatter_kernel<<<NSLICE * NPART_S, 1024, PART_S * sizeof(int), stream>>>(
        row, col, off, countsT, parts2, csr);
    node_kernel<<<(N_NODES + 3) / 4, 256, 0, stream>>>(
        off, parts2, csr, (const unsigned int*)Zb, el, er, out);
}

// Round 18
// 165.694 us; speedup vs baseline: 1.3612x; 1.0254x over previous
//
#include <hip/hip_runtime.h>
#include <hip/hip_bf16.h>
#include <math.h>

#define N_NODES 100000
#define N_EDGES 1600000
#define IN_SIZE 128
#define FEAT 128      // OUT_SIZE * NUM_HEADS
#define HEADS 8
#define SLOPE 0.01f

#define NSLICE 64
#define SLICE_E (N_EDGES / NSLICE)       // 25000
// count: 4 partitions of 25000, packed 16-bit LDS hist (50KB)
#define NPART_C 4
#define PART_C 25000
// scatter: 4 partitions of 25000 (100KB LDS cursor)
#define NPART_S 4
#define PART_S 25000
#define NPARTS_SCAN ((N_NODES + 1023) / 1024)       // 98

#define GBM 128
#define KB 64        // K-half width
#define APA 72       // padded LDS row stride in shorts
#define GEMM_BLOCKS ((N_NODES + GBM - 1) / GBM)     // 782

// bf16 helpers
__device__ __forceinline__ unsigned int f32_to_bf16_rne(float f) {
    unsigned int u = __float_as_uint(f);
    return (u + 0x7FFFu + ((u >> 16) & 1u)) >> 16;
}
__device__ __forceinline__ unsigned int pk_bf16(float lo, float hi) {
    __hip_bfloat162 p = __float22bfloat162_rn(make_float2(lo, hi));
    return *(unsigned int*)&p;
}
__device__ __forceinline__ float bf16lo_to_f32(unsigned int u) {
    return __uint_as_float(u << 16);
}
__device__ __forceinline__ float bf16hi_to_f32(unsigned int u) {
    return __uint_as_float(u & 0xFFFF0000u);
}

typedef __attribute__((ext_vector_type(8))) short short8v;
typedef __attribute__((ext_vector_type(4))) float f32x4;

// ---------------- MFMA bf16 GEMM + register el/er epilogue -------------------
__global__ __launch_bounds__(256) void gemm_mfma(
    const float* __restrict__ x, const float* __restrict__ W,
    const float* __restrict__ bias, const float* __restrict__ al,
    const float* __restrict__ ar, unsigned short* __restrict__ Zb,
    float* __restrict__ el, float* __restrict__ er)
{
    __shared__ unsigned short As[GBM][APA];
    __shared__ unsigned short Bs[FEAT][APA];
    int tid = threadIdx.x;
    int row0 = blockIdx.x * GBM;
    int wv = tid >> 6, l = tid & 63;
    int lr = l & 15, lk = l >> 4;

    f32x4 acc[2][8];
#pragma unroll
    for (int mf = 0; mf < 2; mf++)
#pragma unroll
        for (int nf = 0; nf < 8; nf++) acc[mf][nf] = (f32x4){0.f, 0.f, 0.f, 0.f};

#pragma unroll
    for (int kh = 0; kh < 2; kh++) {
        if (kh) __syncthreads();
#pragma unroll
        for (int i = 0; i < 8; i++) {
            int li = i * 256 + tid;
            int r = li >> 4, c4 = li & 15;
            int grow = row0 + r;
            float4 v = make_float4(0.f, 0.f, 0.f, 0.f);
            if (grow < N_NODES)
                v = *(const float4*)(x + (size_t)grow * IN_SIZE + kh * KB + c4 * 4);
            *(uint2*)&As[r][c4 * 4] = make_uint2(pk_bf16(v.x, v.y), pk_bf16(v.z, v.w));
        }
#pragma unroll
        for (int i = 0; i < 8; i++) {
            int li = i * 256 + tid;
            int f = li >> 4, c4 = li & 15;
            float4 v = *(const float4*)(W + (size_t)f * IN_SIZE + kh * KB + c4 * 4);
            *(uint2*)&Bs[f][c4 * 4] = make_uint2(pk_bf16(v.x, v.y), pk_bf16(v.z, v.w));
        }
        __syncthreads();
#pragma unroll
        for (int ks = 0; ks < 2; ks++) {
            short8v a[2], b[8];
#pragma unroll
            for (int mf = 0; mf < 2; mf++)
                a[mf] = *(const short8v*)&As[wv * 32 + mf * 16 + lr][ks * 32 + lk * 8];
#pragma unroll
            for (int nf = 0; nf < 8; nf++)
                b[nf] = *(const short8v*)&Bs[nf * 16 + lr][ks * 32 + lk * 8];
#pragma unroll
            for (int mf = 0; mf < 2; mf++)
#pragma unroll
                for (int nf = 0; nf < 8; nf++)
                    acc[mf][nf] = __builtin_amdgcn_mfma_f32_16x16x32_bf16(
                        a[mf], b[nf], acc[mf][nf], 0, 0, 0);
        }
    }
    __syncthreads();

    // bias into acc; el/er straight from registers (head = lr&7)
    float bias_r[8], al_r[8], ar_r[8];
#pragma unroll
    for (int nf = 0; nf < 8; nf++) {
        bias_r[nf] = bias[nf * 16 + lr];
        al_r[nf]   = al[nf * 16 + lr];
        ar_r[nf]   = ar[nf * 16 + lr];
    }
#pragma unroll
    for (int mf = 0; mf < 2; mf++)
#pragma unroll
        for (int nf = 0; nf < 8; nf++)
#pragma unroll
            for (int ri = 0; ri < 4; ri++) acc[mf][nf][ri] += bias_r[nf];

#pragma unroll
    for (int mf = 0; mf < 2; mf++)
#pragma unroll
        for (int ri = 0; ri < 4; ri++) {
            float pl = 0.f, pr = 0.f;
#pragma unroll
            for (int nf = 0; nf < 8; nf++) {
                float z = acc[mf][nf][ri];
                pl += z * al_r[nf];
                pr += z * ar_r[nf];
            }
            pl += __shfl_xor(pl, 8, 64);
            pr += __shfl_xor(pr, 8, 64);
            int r = wv * 32 + mf * 16 + lk * 4 + ri;
            int grow = row0 + r;
            if (lr < 8 && grow < N_NODES) {
                el[(size_t)grow * HEADS + lr] = pl;
                er[(size_t)grow * HEADS + lr] = pr;
            }
        }

    // Z (bf16, biased) -> LDS, then coalesced Zb write
#pragma unroll
    for (int mf = 0; mf < 2; mf++)
#pragma unroll
        for (int nf = 0; nf < 8; nf++)
#pragma unroll
            for (int ri = 0; ri < 4; ri++) {
                int r = wv * 32 + mf * 16 + lk * 4 + ri;
                unsigned short zb = (unsigned short)f32_to_bf16_rne(acc[mf][nf][ri]);
                if (nf < 4) As[r][nf * 16 + lr] = zb;
                else        Bs[r][nf * 16 + lr - 64] = zb;
            }
    __syncthreads();
#pragma unroll
    for (int i = 0; i < 8; i++) {
        int li = i * 256 + tid;
        int r = li >> 4, c = li & 15;
        int grow = row0 + r;
        if (grow < N_NODES) {
            uint4 v = (c < 8) ? *(uint4*)&As[r][c * 8]
                              : *(uint4*)&Bs[r][(c - 8) * 8];
            *(uint4*)(Zb + (size_t)grow * FEAT + c * 8) = v;
        }
    }
}

// ---------- CSR build: count with packed 16-bit LDS histogram ----------------
// 4 partitions of 25000 nodes; two 16-bit counts share one u32 (atomicAdd of
// 1 / 0x10000 — per-(s,n) counts <=~10, no carry). row[] re-read 4x not 8x.
__global__ __launch_bounds__(512) void count_kernel(
    const int* __restrict__ row, unsigned char* __restrict__ countsT)
{
    __shared__ unsigned int ldsH[PART_C / 2];   // 50 KB packed
    int tid = threadIdx.x;
    int p = blockIdx.x & (NPART_C - 1);
    int s = blockIdx.x >> 2;
    int lo = p * PART_C;
    for (int i = tid; i < PART_C / 2; i += 512) ldsH[i] = 0;
    __syncthreads();
    int elo = s * SLICE_E;
    for (int e = elo + tid * 4; e < elo + SLICE_E; e += 512 * 4) {
        int4 r4 = *(const int4*)(row + e);
        int r[4] = {r4.x, r4.y, r4.z, r4.w};
#pragma unroll
        for (int i = 0; i < 4; i++) {
            unsigned int d = (unsigned int)(r[i] - lo);
            if (d < PART_C)
                atomicAdd(&ldsH[d >> 1], (d & 1) ? 0x10000u : 1u);
        }
    }
    __syncthreads();
    for (int i = tid; i < PART_C; i += 512) {
        unsigned int v = ldsH[i >> 1];
        countsT[(size_t)s * N_NODES + lo + i] =
            (unsigned char)((i & 1) ? (v >> 16) : (v & 0xffffu));
    }
}

// ---------------- single scan kernel (last-block-done finalization) ----------
__global__ __launch_bounds__(256) void scan_kernel(
    unsigned char* __restrict__ countsT, int* __restrict__ off,
    int* __restrict__ parts, int* __restrict__ parts2, int* __restrict__ ctr)
{
    __shared__ int tsum[256];
    __shared__ int amLast;
    int t = threadIdx.x;
    if (t == 0) amLast = 0;
    int base = blockIdx.x * 1024 + t * 4;
    bool valid = base < N_NODES;
    int run0 = 0, run1 = 0, run2 = 0, run3 = 0;
#pragma unroll 4
    for (int s = 0; s < NSLICE; s++) {
        unsigned char* cp = countsT + (size_t)s * N_NODES + base;
        unsigned int w = valid ? *(const unsigned int*)cp : 0u;
        unsigned int ow = (unsigned int)(run0 & 0xff) | ((unsigned int)(run1 & 0xff) << 8) |
                          ((unsigned int)(run2 & 0xff) << 16) | ((unsigned int)(run3 & 0xff) << 24);
        if (valid) *(unsigned int*)cp = ow;
        run0 += w & 0xffu; run1 += (w >> 8) & 0xffu;
        run2 += (w >> 16) & 0xffu; run3 += (w >> 24) & 0xffu;
    }
    int ssum = run0 + run1 + run2 + run3;
    tsum[t] = ssum;
    __syncthreads();
    for (int st = 1; st < 256; st <<= 1) {
        int add = (t >= st) ? tsum[t - st] : 0;
        __syncthreads();
        tsum[t] += add;
        __syncthreads();
    }
    int texcl = tsum[t] - ssum;
    if (valid) {
        off[base + 0] = texcl;
        off[base + 1] = texcl + run0;
        off[base + 2] = texcl + run0 + run1;
        off[base + 3] = texcl + run0 + run1 + run2;
        if (base + 4 == N_NODES) off[N_NODES] = texcl + ssum;
    }
    if (t == 255) {
        parts[blockIdx.x] = tsum[255];
        __threadfence();
        if (atomicAdd(ctr, 1) == NPARTS_SCAN - 1) amLast = 1;
    }
    __syncthreads();
    if (amLast) {
        __threadfence();
        int v = (t < NPARTS_SCAN) ? parts[t] : 0;
        tsum[t] = v;
        __syncthreads();
        for (int st = 1; st < 128; st <<= 1) {
            int add = (t >= st) ? tsum[t - st] : 0;
            __syncthreads();
            tsum[t] += add;
            __syncthreads();
        }
        if (t < NPARTS_SCAN) parts2[t] = (t > 0) ? tsum[t - 1] : 0;
    }
}

// scatter: 4 partitions x 64 slices; LDS cursor (100KB), LDS atomics only
__global__ __launch_bounds__(1024) void scatter_kernel(
    const int* __restrict__ row, const int* __restrict__ col,
    const int* __restrict__ off, const unsigned char* __restrict__ countsT,
    const int* __restrict__ parts2, int* __restrict__ csr)
{
    extern __shared__ int cur[];   // PART_S ints = 100 KB
    int tid = threadIdx.x;
    int p = blockIdx.x & (NPART_S - 1);
    int s = blockIdx.x >> 2;
    int lo = p * PART_S;
    for (int i = tid; i < PART_S; i += 1024) {
        int n = lo + i;
        cur[i] = off[n] + parts2[n >> 10] + (int)countsT[(size_t)s * N_NODES + n];
    }
    __syncthreads();
    int elo = s * SLICE_E;
    for (int e = elo + tid * 4; e < elo + SLICE_E; e += 1024 * 4) {
        int4 r4 = *(const int4*)(row + e);
        int4 c4 = *(const int4*)(col + e);
        int r[4] = {r4.x, r4.y, r4.z, r4.w};
        int c[4] = {c4.x, c4.y, c4.z, c4.w};
#pragma unroll
        for (int i = 0; i < 4; i++) {
            unsigned int d = (unsigned int)(r[i] - lo);
            if (d < PART_S) {
                int pos = atomicAdd(&cur[d], 1);
                csr[pos] = c[i];
            }
        }
    }
}

// ---------- node kernel: wave-synchronous, 1 wave per node, no LDS -----------
__global__ __launch_bounds__(256) void node_kernel(
    const int* __restrict__ off, const int* __restrict__ parts2,
    const int* __restrict__ csr, const unsigned int* __restrict__ ZbU,
    const float* __restrict__ el, const float* __restrict__ er,
    float* __restrict__ out)
{
    int wv = threadIdx.x >> 6, l = threadIdx.x & 63;
    int n = blockIdx.x * 4 + wv;
    if (n >= N_NODES) return;
    int start = off[n] + parts2[n >> 10];
    int endp  = off[n + 1] + parts2[(n + 1) >> 10];
    int deg = endp - start;
    int l2 = l * 2;
    if (deg == 0) {
        *(float2*)(out + (size_t)n * FEAT + l2) = make_float2(0.f, 0.f);
        return;
    }
    int h = l & 7, jme = l >> 3;
    int h0 = l2 & 7;
    float eln = el[n * HEADS + h];
    float acc0 = 0.f, acc1 = 0.f, sp = 0.f;

    for (int j0 = 0; j0 < deg; j0 += 8) {
        int jn = min(8, deg - j0);
        int jj = l & 7;
        int cidx = (jj < jn) ? (start + j0 + jj) : start;
        int cval = csr[cidx];
        unsigned int zr[8];
#pragma unroll
        for (int j = 0; j < 8; j++) {
            int cj = __shfl(cval, j, 64);
            zr[j] = ZbU[(size_t)cj * 64 + l];
        }
        float ex = 0.f;
        if (jme < jn) {
            int cme = __shfl(cval, jme, 64);
            float a = eln + er[cme * HEADS + h];
            a = (a >= 0.f) ? a : a * SLOPE;
            ex = __expf(a);
            sp += ex;
        }
#pragma unroll
        for (int j = 0; j < 8; j++) {
            float e_lo = __shfl(ex, j * 8 + h0, 64);
            float e_hi = __shfl(ex, j * 8 + h0 + 1, 64);
            acc0 += e_lo * bf16lo_to_f32(zr[j]);
            acc1 += e_hi * bf16hi_to_f32(zr[j]);
        }
    }

    sp += __shfl_xor(sp, 8, 64);
    sp += __shfl_xor(sp, 16, 64);
    sp += __shfl_xor(sp, 32, 64);
    float s_lo = __shfl(sp, h0, 64);
    float s_hi = __shfl(sp, h0 + 1, 64);
    *(float2*)(out + (size_t)n * FEAT + l2) =
        make_float2(acc0 / s_lo, acc1 / s_hi);
}

extern "C" void kernel_launch(void* const* d_in, const int* in_sizes, int n_in,
                              void* d_out, int out_size, void* d_ws, size_t ws_size,
                              hipStream_t stream)
{
    const float* x  = (const float*)d_in[0];
    const float* W  = (const float*)d_in[1];
    const float* b  = (const float*)d_in[2];
    const float* al = (const float*)d_in[3];
    const float* ar = (const float*)d_in[4];
    const int* row  = (const int*)d_in[5];
    const int* col  = (const int*)d_in[6];
    float* out = (float*)d_out;

    unsigned short* Zb = (unsigned short*)d_ws;                    // 25.6 MB
    float* el   = (float*)(Zb + (size_t)N_NODES * FEAT);           // 3.2 MB
    float* er   = el + (size_t)N_NODES * HEADS;                    // 3.2 MB
    unsigned char* countsT = (unsigned char*)(er + (size_t)N_NODES * HEADS); // 6.4 MB
    int* off    = (int*)(countsT + (size_t)NSLICE * N_NODES);      // 400 KB
    int* csr    = off + (N_NODES + 1);                             // 6.4 MB
    int* parts  = csr + N_EDGES;                                   // 128
    int* parts2 = parts + 128;                                     // 128
    int* ctr    = parts2 + 128;                                    // 1

    hipMemsetAsync(ctr, 0, sizeof(int), stream);

    gemm_mfma<<<GEMM_BLOCKS, 256, 0, stream>>>(x, W, b, al, ar, Zb, el, er);
    count_kernel<<<NSLICE * NPART_C, 512, 0, stream>>>(row, countsT);
    scan_kernel<<<NPARTS_SCAN, 256, 0, stream>>>(countsT, off, parts, parts2, ctr);
    scatter_kernel<<<NSLICE * NPART_S, 1024, PART_S * sizeof(int), stream>>>(
        row, col, off, countsT, parts2, csr);
    node_kernel<<<(N_NODES + 3) / 4, 256, 0, stream>>>(
        off, parts2, csr, (const unsigned int*)Zb, el, er, out);
}